// Round 4
// baseline (145.782 us; speedup 1.0000x reference)
//
#include <hip/hip_runtime.h>

// TotalDegree: out[b, t] = prod over multiset term t of x[b, d]; terms = all
// multisets of size 0..4 over 8 vars in lexicographic (sorted-tuple) order.
// Factorization: term = P[u]*P[v], P = 45 multisets of size <= 2, one per lane.
// R3: 4 rows per step -> 7920 B contiguous output, 16-B aligned => 8 aligned
// float4 wave stores (vs 32 misaligned dword stores). Stores 1,3,5 straddle a
// row boundary: both candidate rows' P are bpermuted and selected by a
// compile-time lane threshold. No masked-lane waste except exact 47-lane tail.

struct Specs {
    unsigned kspec[8][64][2];  // [k][lane][{slots01,slots23}], 16b/slot: u<<2 | (v<<2)<<8
    unsigned short pp[64];     // per lane: s1 | s2<<4 | use1<<8 | use2<<9
};

constexpr int pidx_c(int a, int b) {
    return 9 + 8 * a - (a * (a - 1)) / 2 + (b - a);  // empty=0, singles=1..8, pairs 9..44
}

constexpr Specs make_specs() {
    Specs S{};
    for (int l = 0; l < 64; ++l) {
        int s1 = 0, s2 = 0, u1 = 0, u2 = 0;
        if (l >= 1 && l <= 8) { s1 = l - 1; u1 = 1; }
        else if (l >= 9 && l < 45) {
            int k = l - 9, i = 0;
            while (k >= 8 - i) { k -= 8 - i; ++i; }
            s1 = i; s2 = i + k; u1 = 1; u2 = 1;
        }
        S.pp[l] = (unsigned short)(s1 | (s2 << 4) | (u1 << 8) | (u2 << 9));
    }
    // Term table via DFS preorder over non-decreasing tuples == reference order.
    unsigned short uv[495] = {};  // u | v<<8 ; term 0 = empty -> u=v=0 (P[0]=1)
    int idx = 1;
    for (int a = 0; a < 8; ++a) {
        uv[idx++] = (unsigned short)(1 + a);
        for (int b = a; b < 8; ++b) {
            uv[idx++] = (unsigned short)pidx_c(a, b);
            for (int c = b; c < 8; ++c) {
                uv[idx++] = (unsigned short)(pidx_c(a, b) | ((1 + c) << 8));
                for (int d = c; d < 8; ++d)
                    uv[idx++] = (unsigned short)(pidx_c(a, b) | (pidx_c(c, d) << 8));
            }
        }
    }
    // Per-store-k, per-lane slot specs over a 4-row (1980-elem) group.
    for (int k = 0; k < 8; ++k)
        for (int l = 0; l < 64; ++l) {
            unsigned w0 = 0, w1 = 0;
            for (int s = 0; s < 4; ++s) {
                int e = k * 256 + l * 4 + s;
                unsigned field = 0;
                if (e < 1980) {
                    int t = e % 495;
                    unsigned u = uv[t] & 255u, v = uv[t] >> 8;
                    field = (u << 2) | ((v << 2) << 8);  // pre-scaled byte addrs
                }
                if (s < 2) w0 |= field << (s * 16);
                else       w1 |= field << ((s - 2) * 16);
            }
            S.kspec[k][l][0] = w0;
            S.kspec[k][l][1] = w1;
        }
    return S;
}

__constant__ Specs SPECS = make_specs();

#define WAVES_PER_BLOCK 4
#define ROWS_PER_WAVE   8          // = 2 groups of 4 rows
#define ROWS_PER_BLOCK  (WAVES_PER_BLOCK * ROWS_PER_WAVE)  // 32

__global__ __launch_bounds__(256, 8) void TotalDegree_29755533426739_kernel(
    const float* __restrict__ x, float* __restrict__ out, int B) {
    __shared__ float xs[ROWS_PER_BLOCK * 8];  // 1 KB x-tile

    const int tid  = (int)threadIdx.x;
    const int lane = tid & 63;
    const int wid  = tid >> 6;

    // Bulk coalesced x-tile load.
    {
        const int gi = (int)blockIdx.x * (ROWS_PER_BLOCK * 8) + tid;
        xs[tid] = (gi < B * 8) ? x[gi] : 0.0f;
    }

    // Per-lane row-invariant constants.
    const int ppv  = (int)SPECS.pp[lane];
    const int s1   = ppv & 15;
    const int s2   = (ppv >> 4) & 15;
    const bool use1 = ((ppv >> 8) & 1) != 0;
    const bool use2 = ((ppv >> 9) & 1) != 0;

    unsigned kw0[8], kw1[8];  // slot specs, 16 VGPRs, loaded once (L1-cached)
    #pragma unroll
    for (int k = 0; k < 8; ++k) {
        kw0[k] = SPECS.kspec[k][lane][0];
        kw1[k] = SPECS.kspec[k][lane][1];
    }

    __syncthreads();

    // Per-k row indices and boundary lane thresholds (compile-time).
    constexpr int RA[8]  = {0, 0, 1, 1, 2, 2, 3, 3};
    constexpr int RB[8]  = {0, 1, 1, 2, 2, 3, 3, 3};
    constexpr int THR[8] = {0, 239, 0, 222, 0, 205, 0, 0};  // rb*495 - k*256

    const float* xw = xs + wid * (ROWS_PER_WAVE * 8);
    const unsigned grp0 =
        ((unsigned)blockIdx.x * ROWS_PER_BLOCK + (unsigned)(wid * ROWS_PER_WAVE)) >> 2;

    #pragma unroll
    for (int gg = 0; gg < ROWS_PER_WAVE / 4; ++gg) {
        const unsigned grp = grp0 + (unsigned)gg;
        if ((int)(grp * 4) >= B) break;

        // P for the group's 4 rows (one value per lane per row).
        float Pr[4];
        #pragma unroll
        for (int r = 0; r < 4; ++r) {
            const int xb = (gg * 4 + r) * 8;
            const float a1 = xw[xb + s1];
            const float a2 = xw[xb + s2];
            Pr[r] = (use1 ? a1 : 1.0f) * (use2 ? a2 : 1.0f);
        }

        float* gbase = out + (size_t)grp * 1980u;  // 16-B aligned (1980*4 = 495*16)

        #pragma unroll
        for (int k = 0; k < 8; ++k) {
            const int PaI = __float_as_int(Pr[RA[k]]);
            const int PbI = __float_as_int(Pr[RB[k]]);
            float4 val;
            #pragma unroll
            for (int s = 0; s < 4; ++s) {
                const unsigned w = (s < 2) ? kw0[k] : kw1[k];
                const unsigned field = (s & 1) ? (w >> 16) : (w & 0xffffu);
                const int u4 = (int)(field & 0xffu);
                const int v4 = (int)((field >> 8) & 0xffu);
                float f1 = __int_as_float(__builtin_amdgcn_ds_bpermute(u4, PaI));
                float f2 = __int_as_float(__builtin_amdgcn_ds_bpermute(v4, PaI));
                if (RA[k] != RB[k]) {  // boundary-crossing store: select per lane
                    const float g1 = __int_as_float(__builtin_amdgcn_ds_bpermute(u4, PbI));
                    const float g2 = __int_as_float(__builtin_amdgcn_ds_bpermute(v4, PbI));
                    const bool useA = lane < ((THR[k] - s + 3) >> 2);
                    f1 = useA ? f1 : g1;
                    f2 = useA ? f2 : g2;
                }
                (&val.x)[s] = f1 * f2;
            }
            if (k < 7) {
                *(float4*)(gbase + k * 256 + lane * 4) = val;   // aligned dwordx4
            } else if (lane < 47) {                              // exact tail: 188 elems
                *(float4*)(gbase + 1792 + lane * 4) = val;
            }
        }
    }
}

extern "C" void kernel_launch(void* const* d_in, const int* in_sizes, int n_in,
                              void* d_out, int out_size, void* d_ws, size_t ws_size,
                              hipStream_t stream) {
    const float* x = (const float*)d_in[0];
    float* out = (float*)d_out;
    const int B = in_sizes[0] / 8;  // 65536 rows
    const int grid = (B + ROWS_PER_BLOCK - 1) / ROWS_PER_BLOCK;  // 2048
    hipLaunchKernelGGL(TotalDegree_29755533426739_kernel,
                       dim3(grid), dim3(256), 0, stream, x, out, B);
}